// Round 1
// baseline (441.544 us; speedup 1.0000x reference)
//
#include <hip/hip_runtime.h>
#include <cstdint>
#include <cstddef>

#define NN 50000
#define NE 800000
#define CAP 96      // max in-degree bucket capacity (Poisson(16): P(deg>=96) ~ 1e-42)
#define TP 68       // padded LDS tile stride (16B-aligned, breaks pow2 bank stride)

// ---------------- ws layout (units of 4 bytes) ----------------
constexpr size_t O_CNT   = 0;                       // int[NN]
constexpr size_t O_SLOT  = 50048;                   // int[NN*CAP]
constexpr size_t O_DINV  = O_SLOT + (size_t)NN*CAP; // rsqrt(deg+1)
constexpr size_t O_DINVC = O_DINV + 50048;          // rsqrt(max(deg,1))
constexpr size_t O_INVD  = O_DINVC + 50048;         // 1/max(deg,1)
constexpr size_t O_EL    = O_INVD + 50048;
constexpr size_t O_ER    = O_EL + 50048;
constexpr size_t O_M     = O_ER + 50048;
constexpr size_t O_XW    = O_M + 50048;             // x @ W_gcn
constexpr size_t O_H     = O_XW + 3200000;          // x @ W_gat
constexpr size_t O_NS    = O_H + 3200000;           // nsum
constexpr size_t O_T1    = O_NS + 3200000;
constexpr size_t O_T2    = O_T1 + 3200000;
constexpr size_t O_GCN   = O_T2 + 3200000;          // gcn pre-bias
constexpr size_t O_GAT   = O_GCN + 3200000;         // gat pre-bias
// total ~110.2 MB

__device__ __forceinline__ float leaky02(float v){ return v >= 0.f ? v : 0.2f*v; }
__device__ __forceinline__ float eluf(float v){ return v > 0.f ? v : expm1f(v); }

// ---------------- bucket build ----------------
__global__ void k_zero(int* __restrict__ cnt){
  int i = blockIdx.x*256 + threadIdx.x;
  if (i < NN) cnt[i] = 0;
}

__global__ void k_scatter(const int* __restrict__ src, const int* __restrict__ dst,
                          int* __restrict__ cnt, int* __restrict__ slot){
  int e = blockIdx.x*256 + threadIdx.x;
  if (e >= NE) return;
  int s = src[e], d = dst[e];
  int pos = atomicAdd(&cnt[d], 1);
  if (pos < CAP) slot[(size_t)d*CAP + pos] = s;
}

__global__ void k_nodeprep(const int* __restrict__ cnt, float* __restrict__ dinv,
                           float* __restrict__ dinvc, float* __restrict__ invd){
  int n = blockIdx.x*256 + threadIdx.x;
  if (n >= NN) return;
  float c = (float)cnt[n];
  dinv[n]  = rsqrtf(c + 1.f);
  float cm = fmaxf(c, 1.f);
  dinvc[n] = rsqrtf(cm);
  invd[n]  = 1.f / cm;
}

// ---------------- tiled GEMV helpers ----------------
__device__ __forceinline__ void load_tile(const float* __restrict__ g, int r0,
                                          float (*__restrict__ sm)[TP], int tid){
  #pragma unroll
  for (int i = 0; i < 4; ++i){
    int idx = i*256 + tid;
    int r = idx >> 4, c4 = idx & 15;
    float4 v = make_float4(0.f,0.f,0.f,0.f);
    if (r0 + r < NN) v = *(const float4*)&g[(size_t)(r0+r)*64 + c4*4];
    *(float4*)&sm[r][c4*4] = v;
  }
}

__device__ __forceinline__ void load_w(const float* __restrict__ w,
                                       float (*__restrict__ sm)[TP], int tid){
  #pragma unroll
  for (int i = 0; i < 4; ++i){
    int idx = i*256 + tid;
    int r = idx >> 4, c4 = idx & 15;
    *(float4*)&sm[r][c4*4] = *(const float4*)&w[(size_t)r*64 + c4*4];
  }
}

__device__ __forceinline__ void gemv_tile(const float (*__restrict__ sA)[TP],
                                          const float (*__restrict__ sW)[TP],
                                          float4 o[4], int r4, int c4){
  #pragma unroll 4
  for (int k4 = 0; k4 < 16; ++k4){
    float4 w0 = *(const float4*)&sW[k4*4+0][c4*4];
    float4 w1 = *(const float4*)&sW[k4*4+1][c4*4];
    float4 w2 = *(const float4*)&sW[k4*4+2][c4*4];
    float4 w3 = *(const float4*)&sW[k4*4+3][c4*4];
    #pragma unroll
    for (int i = 0; i < 4; ++i){
      float4 a = *(const float4*)&sA[r4*4+i][k4*4];
      o[i].x = fmaf(a.x,w0.x, fmaf(a.y,w1.x, fmaf(a.z,w2.x, fmaf(a.w,w3.x, o[i].x))));
      o[i].y = fmaf(a.x,w0.y, fmaf(a.y,w1.y, fmaf(a.z,w2.y, fmaf(a.w,w3.y, o[i].y))));
      o[i].z = fmaf(a.x,w0.z, fmaf(a.y,w1.z, fmaf(a.z,w2.z, fmaf(a.w,w3.z, o[i].z))));
      o[i].w = fmaf(a.x,w0.w, fmaf(a.y,w1.w, fmaf(a.z,w2.w, fmaf(a.w,w3.w, o[i].w))));
    }
  }
}

__device__ __forceinline__ void zero4(float4 o[4]){
  #pragma unroll
  for (int i=0;i<4;++i) o[i] = make_float4(0.f,0.f,0.f,0.f);
}

__device__ __forceinline__ void acc_elu(float4 res[4], const float4 o[4], float4 b, float w){
  #pragma unroll
  for (int i=0;i<4;++i){
    res[i].x += w * eluf(o[i].x + b.x);
    res[i].y += w * eluf(o[i].y + b.y);
    res[i].z += w * eluf(o[i].z + b.z);
    res[i].w += w * eluf(o[i].w + b.w);
  }
}

// ---------------- phase 1: xw = x@W_gcn, h = x@W_gat ----------------
__global__ __launch_bounds__(256) void k_phase1(const float* __restrict__ x,
    const float* __restrict__ Wg, const float* __restrict__ Wa,
    float* __restrict__ xw, float* __restrict__ h){
  __shared__ float sX[64][TP];
  __shared__ float sW[64][TP];
  int tid = threadIdx.x, r0 = blockIdx.x*64;
  int c4 = tid & 15, r4 = tid >> 4;
  load_tile(x, r0, sX, tid);
  load_w(Wg, sW, tid);
  __syncthreads();
  float4 o[4]; zero4(o);
  gemv_tile(sX, sW, o, r4, c4);
  #pragma unroll
  for (int i=0;i<4;++i){ int row=r0+r4*4+i; if(row<NN) *(float4*)&xw[(size_t)row*64+c4*4]=o[i]; }
  __syncthreads();
  load_w(Wa, sW, tid);
  __syncthreads();
  zero4(o);
  gemv_tile(sX, sW, o, r4, c4);
  #pragma unroll
  for (int i=0;i<4;++i){ int row=r0+r4*4+i; if(row<NN) *(float4*)&h[(size_t)row*64+c4*4]=o[i]; }
}

// ---------------- el/er = h @ a_src, h @ a_dst ----------------
__global__ __launch_bounds__(256) void k_elr(const float* __restrict__ h,
    const float* __restrict__ a_src, const float* __restrict__ a_dst,
    float* __restrict__ el, float* __restrict__ er){
  int tid = threadIdx.x;
  int li = tid & 15;
  int row = blockIdx.x*16 + (tid >> 4);
  float4 hv = *(const float4*)&h[(size_t)row*64 + li*4];
  float4 as = *(const float4*)&a_src[li*4];
  float4 ad = *(const float4*)&a_dst[li*4];
  float ps = hv.x*as.x + hv.y*as.y + hv.z*as.z + hv.w*as.w;
  float pd = hv.x*ad.x + hv.y*ad.y + hv.z*ad.z + hv.w*ad.w;
  #pragma unroll
  for (int o=1;o<16;o<<=1){ ps += __shfl_xor(ps,o); pd += __shfl_xor(pd,o); }
  if (li == 0){ el[row] = ps; er[row] = pd; }
}

// ---------------- agg1: nsum, T1 ----------------
__global__ __launch_bounds__(256) void k_agg1(const float* __restrict__ x,
    const int* __restrict__ cnt, const int* __restrict__ slot,
    const float* __restrict__ dinvc, float* __restrict__ nsum, float* __restrict__ T1){
  int node = blockIdx.x*4 + (threadIdx.x >> 6);
  int lane = threadIdx.x & 63;
  if (node >= NN) return;
  int c = min(cnt[node], CAP);
  const int* sl = slot + (size_t)node*CAP;
  float a0 = 0.f, a1 = 0.f;
  for (int base = 0; base < c; base += 64){
    int rem = min(64, c - base);
    int s = (lane < rem) ? sl[base+lane] : 0;
    float dc = (lane < rem) ? dinvc[s] : 0.f;
    for (int j = 0; j < rem; ++j){
      int sb = __shfl(s, j);
      float dcb = __shfl(dc, j);
      float v = x[(size_t)sb*64 + lane];
      a0 += v;
      a1 += dcb * v;
    }
  }
  float dcn = dinvc[node];
  nsum[(size_t)node*64+lane] = a0;
  T1[(size_t)node*64+lane]   = -dcn * a1;
}

// ---------------- agg2: gcn_pre, T2, gat max(m) ----------------
__global__ __launch_bounds__(256) void k_agg2(const float* __restrict__ x,
    const float* __restrict__ xw, const float* __restrict__ T1,
    const int* __restrict__ cnt, const int* __restrict__ slot,
    const float* __restrict__ dinv, const float* __restrict__ dinvc,
    const float* __restrict__ el, const float* __restrict__ er,
    float* __restrict__ gcn_pre, float* __restrict__ T2, float* __restrict__ m_out){
  int node = blockIdx.x*4 + (threadIdx.x >> 6);
  int lane = threadIdx.x & 63;
  if (node >= NN) return;
  int c = min(cnt[node], CAP);
  const int* sl = slot + (size_t)node*CAP;
  float ern = er[node];
  float ag = 0.f, as2 = 0.f, mx = -1e30f;
  for (int base = 0; base < c; base += 64){
    int rem = min(64, c - base);
    int s = (lane < rem) ? sl[base+lane] : 0;
    float elv = (lane < rem) ? el[s] : -1e30f;
    float dv  = (lane < rem) ? dinv[s]  : 0.f;
    float dcv = (lane < rem) ? dinvc[s] : 0.f;
    float e = leaky02(elv + ern);
    if (lane >= rem) e = -1e30f;
    float red = e;
    #pragma unroll
    for (int o=32;o>0;o>>=1) red = fmaxf(red, __shfl_xor(red, o));
    mx = fmaxf(mx, red);
    for (int j = 0; j < rem; ++j){
      int sb = __shfl(s, j);
      float dvb = __shfl(dv, j);
      float dcb = __shfl(dcv, j);
      ag  += dvb * xw[(size_t)sb*64 + lane];
      as2 += dcb * T1[(size_t)sb*64 + lane];
    }
  }
  float es = leaky02(el[node] + ern);
  mx = fmaxf(mx, es);
  if (lane == 0) m_out[node] = mx;
  float dn = dinv[node];
  gcn_pre[(size_t)node*64+lane] = dn*ag + dn*dn*xw[(size_t)node*64+lane];
  float dcn = dinvc[node];
  T2[(size_t)node*64+lane] = -2.f*dcn*as2 - x[(size_t)node*64+lane];
}

// ---------------- agg3: gat_pre ----------------
__global__ __launch_bounds__(256) void k_agg3(const float* __restrict__ h,
    const int* __restrict__ cnt, const int* __restrict__ slot,
    const float* __restrict__ el, const float* __restrict__ er,
    const float* __restrict__ m_in, float* __restrict__ gat_pre){
  int node = blockIdx.x*4 + (threadIdx.x >> 6);
  int lane = threadIdx.x & 63;
  if (node >= NN) return;
  int c = min(cnt[node], CAP);
  const int* sl = slot + (size_t)node*CAP;
  float ern = er[node], mn = m_in[node];
  float acc = 0.f, z = 0.f;
  for (int base = 0; base < c; base += 64){
    int rem = min(64, c - base);
    int s = (lane < rem) ? sl[base+lane] : 0;
    float elv = (lane < rem) ? el[s] : 0.f;
    float p = (lane < rem) ? __expf(leaky02(elv + ern) - mn) : 0.f;
    for (int j = 0; j < rem; ++j){
      int sb = __shfl(s, j);
      float pb = __shfl(p, j);
      acc += pb * h[(size_t)sb*64 + lane];
      z += pb;
    }
  }
  float ps = __expf(leaky02(el[node] + ern) - mn);
  acc += ps * h[(size_t)node*64 + lane];
  z += ps;
  gat_pre[(size_t)node*64+lane] = acc / (z + 1e-16f);
}

// ---------------- epilogue: all remaining GEMVs + elu-combine ----------------
__global__ __launch_bounds__(256) void k_epi(
    const float* __restrict__ x, const float* __restrict__ wts,
    const float* __restrict__ W_mlp, const float* __restrict__ b_mlp,
    const float* __restrict__ Wl, const float* __restrict__ Wr, const float* __restrict__ b_sage,
    const float* __restrict__ b_gcn, const float* __restrict__ b_gat,
    const float* __restrict__ W_cheb, const float* __restrict__ b_cheb,
    const float* __restrict__ W_gin, const float* __restrict__ b_gin,
    const float* __restrict__ nsum, const int* __restrict__ cnt, const float* __restrict__ invd,
    const float* __restrict__ T1, const float* __restrict__ T2,
    const float* __restrict__ gcn_pre, const float* __restrict__ gat_pre,
    float* __restrict__ out){
  __shared__ float sX[64][TP];
  __shared__ float sA[64][TP];
  __shared__ float sW[64][TP];
  int tid = threadIdx.x, r0 = blockIdx.x*64;
  int c4 = tid & 15, r4 = tid >> 4;
  float w0 = wts[0], w1 = wts[1], w2 = wts[2], w3 = wts[3], w4 = wts[4], w5 = wts[5];

  float4 res[4]; zero4(res);
  float4 o[4];

  load_tile(x, r0, sX, tid);
  load_w(W_mlp, sW, tid);
  __syncthreads();
  // --- mlp ---
  zero4(o);
  gemv_tile(sX, sW, o, r4, c4);
  acc_elu(res, o, *(const float4*)&b_mlp[c4*4], w0);
  __syncthreads();
  // --- sage: nmean@Wl + x@Wr ---
  load_w(Wl, sW, tid);
  load_tile(nsum, r0, sA, tid);
  #pragma unroll
  for (int i=0;i<4;++i){           // scale rows by 1/max(deg,1) (same-thread positions)
    int idx=i*256+tid; int r=idx>>4, cc=idx&15; int row=r0+r;
    float sc = (row<NN)? invd[row] : 0.f;
    float4 v = *(float4*)&sA[r][cc*4];
    v.x*=sc; v.y*=sc; v.z*=sc; v.w*=sc;
    *(float4*)&sA[r][cc*4]=v;
  }
  __syncthreads();
  zero4(o);
  gemv_tile(sA, sW, o, r4, c4);
  __syncthreads();
  load_w(Wr, sW, tid);
  __syncthreads();
  gemv_tile(sX, sW, o, r4, c4);
  acc_elu(res, o, *(const float4*)&b_sage[c4*4], w1);
  // --- gcn + gat (precomputed aggregates, direct global) ---
  {
    float4 bg = *(const float4*)&b_gcn[c4*4];
    float4 ba = *(const float4*)&b_gat[c4*4];
    #pragma unroll
    for (int i=0;i<4;++i){
      int row = r0 + r4*4 + i;
      if (row < NN){
        float4 g = *(const float4*)&gcn_pre[(size_t)row*64 + c4*4];
        float4 t = *(const float4*)&gat_pre[(size_t)row*64 + c4*4];
        res[i].x += w2*eluf(g.x+bg.x) + w3*eluf(t.x+ba.x);
        res[i].y += w2*eluf(g.y+bg.y) + w3*eluf(t.y+ba.y);
        res[i].z += w2*eluf(g.z+bg.z) + w3*eluf(t.z+ba.z);
        res[i].w += w2*eluf(g.w+bg.w) + w3*eluf(t.w+ba.w);
      }
    }
  }
  // --- cheb: x@W0 + T1@W1 + T2@W2 ---
  __syncthreads();
  load_w(W_cheb, sW, tid);
  __syncthreads();
  zero4(o);
  gemv_tile(sX, sW, o, r4, c4);
  __syncthreads();
  load_w(W_cheb + 4096, sW, tid);
  load_tile(T1, r0, sA, tid);
  __syncthreads();
  gemv_tile(sA, sW, o, r4, c4);
  __syncthreads();
  load_w(W_cheb + 8192, sW, tid);
  load_tile(T2, r0, sA, tid);
  __syncthreads();
  gemv_tile(sA, sW, o, r4, c4);
  acc_elu(res, o, *(const float4*)&b_cheb[c4*4], w4);
  // --- gin: (x+nsum)@W_gin ---
  __syncthreads();
  load_w(W_gin, sW, tid);
  load_tile(nsum, r0, sA, tid);
  #pragma unroll
  for (int i=0;i<4;++i){
    int idx=i*256+tid; int r=idx>>4, cc=idx&15;
    float4 v = *(float4*)&sA[r][cc*4];
    float4 xv = *(const float4*)&sX[r][cc*4];
    v.x+=xv.x; v.y+=xv.y; v.z+=xv.z; v.w+=xv.w;
    *(float4*)&sA[r][cc*4]=v;
  }
  __syncthreads();
  zero4(o);
  gemv_tile(sA, sW, o, r4, c4);
  acc_elu(res, o, *(const float4*)&b_gin[c4*4], w5);
  // --- store ---
  #pragma unroll
  for (int i=0;i<4;++i){
    int row = r0 + r4*4 + i;
    if (row < NN) *(float4*)&out[(size_t)row*64 + c4*4] = res[i];
  }
}

extern "C" void kernel_launch(void* const* d_in, const int* in_sizes, int n_in,
                              void* d_out, int out_size, void* d_ws, size_t ws_size,
                              hipStream_t stream){
  const float* x      = (const float*)d_in[0];
  const float* wts    = (const float*)d_in[1];
  const float* W_mlp  = (const float*)d_in[2];
  const float* b_mlp  = (const float*)d_in[3];
  const float* Wl     = (const float*)d_in[4];
  const float* Wr     = (const float*)d_in[5];
  const float* b_sage = (const float*)d_in[6];
  const float* W_gcn  = (const float*)d_in[7];
  const float* b_gcn  = (const float*)d_in[8];
  const float* W_gat  = (const float*)d_in[9];
  const float* a_src  = (const float*)d_in[10];
  const float* a_dst  = (const float*)d_in[11];
  const float* b_gat  = (const float*)d_in[12];
  const float* W_cheb = (const float*)d_in[13];
  const float* b_cheb = (const float*)d_in[14];
  const float* W_gin  = (const float*)d_in[15];
  const float* b_gin  = (const float*)d_in[16];
  const int*   ei     = (const int*)d_in[17];
  const int* srcp = ei;
  const int* dstp = ei + NE;

  float* wsf  = (float*)d_ws;
  int*  cnt   = (int*)d_ws;
  int*  slot  = (int*)(wsf + O_SLOT);
  float* dinv  = wsf + O_DINV;
  float* dinvc = wsf + O_DINVC;
  float* invd  = wsf + O_INVD;
  float* el    = wsf + O_EL;
  float* er    = wsf + O_ER;
  float* m     = wsf + O_M;
  float* xw    = wsf + O_XW;
  float* h     = wsf + O_H;
  float* nsum  = wsf + O_NS;
  float* T1    = wsf + O_T1;
  float* T2    = wsf + O_T2;
  float* gcnp  = wsf + O_GCN;
  float* gatp  = wsf + O_GAT;
  float* out   = (float*)d_out;

  k_zero    <<<196,  256, 0, stream>>>(cnt);
  k_scatter <<<3125, 256, 0, stream>>>(srcp, dstp, cnt, slot);
  k_nodeprep<<<196,  256, 0, stream>>>(cnt, dinv, dinvc, invd);
  k_phase1  <<<782,  256, 0, stream>>>(x, W_gcn, W_gat, xw, h);
  k_elr     <<<3125, 256, 0, stream>>>(h, a_src, a_dst, el, er);
  k_agg1    <<<12500,256, 0, stream>>>(x, cnt, slot, dinvc, nsum, T1);
  k_agg2    <<<12500,256, 0, stream>>>(x, xw, T1, cnt, slot, dinv, dinvc, el, er, gcnp, T2, m);
  k_agg3    <<<12500,256, 0, stream>>>(h, cnt, slot, el, er, m, gatp);
  k_epi     <<<782,  256, 0, stream>>>(x, wts, W_mlp, b_mlp, Wl, Wr, b_sage, b_gcn, b_gat,
                                       W_cheb, b_cheb, W_gin, b_gin,
                                       nsum, cnt, invd, T1, T2, gcnp, gatp, out);
}

// Round 2
// 375.978 us; speedup vs baseline: 1.1744x; 1.1744x over previous
//
#include <hip/hip_runtime.h>
#include <cstdint>
#include <cstddef>

#define NN 50000
#define NE 800000
#define CAP 96      // max in-degree bucket (Poisson(16): P(deg>=96) ~ 1e-42)
#define TP 68       // padded LDS tile stride

// ---------------- ws layout (units of 4 bytes) ----------------
constexpr size_t O_CNT   = 0;                        // int[NN]
constexpr size_t O_SLOT  = 50048;                    // int[NN*CAP]
constexpr size_t O_NODAL = O_SLOT + (size_t)NN*CAP;  // float4[NN] {dinvc,dinv,el,er}
constexpr size_t O_VA    = O_NODAL + 200000;         // 64
constexpr size_t O_VB    = O_VA + 64;                // 64
constexpr size_t O_NS    = O_VB + 64;                // nsum [N,64]
constexpr size_t O_T1    = O_NS + 3200000;
constexpr size_t O_V1    = O_T1 + 3200000;           // gcn A-vector
constexpr size_t O_G     = O_V1 + 3200000;           // gat A-vector
constexpr size_t O_U     = O_G  + 3200000;           // -2*dinvc*aggT (T2 = u - x)
// total ~84.2 MB

__device__ __forceinline__ float leaky02(float v){ return v >= 0.f ? v : 0.2f*v; }
__device__ __forceinline__ float eluf(float v){ return v > 0.f ? v : expm1f(v); }

// ---------------- bucket build ----------------
__global__ void k_scatter(const int* __restrict__ src, const int* __restrict__ dst,
                          int* __restrict__ cnt, int* __restrict__ slot){
  int e = blockIdx.x*256 + threadIdx.x;
  if (e >= NE) return;
  int s = src[e], d = dst[e];
  int pos = atomicAdd(&cnt[d], 1);
  if (pos < CAP) slot[(size_t)d*CAP + pos] = s;
}

// ---------------- va = W_gat @ a_src, vb = W_gat @ a_dst ----------------
__global__ void k_va(const float* __restrict__ Wg, const float* __restrict__ a_src,
                     const float* __restrict__ a_dst, float* __restrict__ va, float* __restrict__ vb){
  int k = threadIdx.x;   // 64 threads
  float sa = 0.f, sb = 0.f;
  for (int j = 0; j < 64; ++j){
    float w = Wg[k*64 + j];
    sa = fmaf(w, a_src[j], sa);
    sb = fmaf(w, a_dst[j], sb);
  }
  va[k] = sa; vb[k] = sb;
}

// ---------------- per-node scalars: {dinvc, dinv, el, er} ----------------
__global__ __launch_bounds__(256) void k_nodal(const float* __restrict__ x,
    const int* __restrict__ cnt, const float* __restrict__ va, const float* __restrict__ vb,
    float4* __restrict__ nodal){
  int tid = threadIdx.x;
  int li = tid & 15;
  int row = blockIdx.x*16 + (tid >> 4);
  if (row >= NN) return;
  float4 hv = *(const float4*)&x[(size_t)row*64 + li*4];
  float4 av = *(const float4*)&va[li*4];
  float4 bv = *(const float4*)&vb[li*4];
  float ps = hv.x*av.x + hv.y*av.y + hv.z*av.z + hv.w*av.w;
  float pd = hv.x*bv.x + hv.y*bv.y + hv.z*bv.z + hv.w*bv.w;
  #pragma unroll
  for (int o = 1; o < 16; o <<= 1){ ps += __shfl_xor(ps, o); pd += __shfl_xor(pd, o); }
  if (li == 0){
    float c = (float)cnt[row];
    float dinv  = rsqrtf(c + 1.f);
    float dinvc = rsqrtf(fmaxf(c, 1.f));
    nodal[row] = make_float4(dinvc, dinv, ps, pd);
  }
}

// ---------------- pass A: fused gather of x -> nsum, T1, v1(gcn), g(gat) ----------------
__global__ __launch_bounds__(256) void k_aggA(const float* __restrict__ x,
    const int* __restrict__ cnt, const int* __restrict__ slot,
    const float4* __restrict__ nodal,
    float* __restrict__ nsum, float* __restrict__ T1,
    float* __restrict__ v1, float* __restrict__ g){
  int node = blockIdx.x*4 + (threadIdx.x >> 6);
  int lane = threadIdx.x & 63;
  if (node >= NN) return;
  int c = min(cnt[node], CAP);
  const int* sl = slot + (size_t)node*CAP;
  float4 nn = nodal[node];         // {dinvc, dinv, el, er}
  float ern = nn.w;
  float a0 = 0.f, a1 = 0.f, a2 = 0.f, a3 = 0.f, zl = 0.f;
  for (int base = 0; base < c; base += 64){
    int rem = min(64, c - base);
    bool act = lane < rem;
    int s = act ? sl[base+lane] : 0;
    float4 ns = act ? nodal[s] : make_float4(0.f,0.f,0.f,0.f);
    float p = act ? __expf(fminf(leaky02(ns.z + ern), 60.f)) : 0.f;
    zl += p;
    for (int j = 0; j < rem; ++j){
      int sb    = __shfl(s, j);
      float dcb = __shfl(ns.x, j);
      float dvb = __shfl(ns.y, j);
      float pb  = __shfl(p, j);
      float v = x[(size_t)sb*64 + lane];
      a0 += v;
      a1 = fmaf(dcb, v, a1);
      a2 = fmaf(dvb, v, a2);
      a3 = fmaf(pb,  v, a3);
    }
  }
  #pragma unroll
  for (int o = 32; o > 0; o >>= 1) zl += __shfl_xor(zl, o);
  float xs = x[(size_t)node*64 + lane];
  float p_self = __expf(fminf(leaky02(nn.z + nn.w), 60.f));
  float rz = 1.f / (zl + p_self + 1e-16f);
  size_t off = (size_t)node*64 + lane;
  nsum[off] = a0;
  T1[off]   = -nn.x * a1;
  v1[off]   = nn.y*a2 + nn.y*nn.y*xs;
  g[off]    = (a3 + p_self*xs) * rz;
}

// ---------------- pass B: gather T1 -> u = -2*dinvc*Σ dinvc[s] T1[s] ----------------
__global__ __launch_bounds__(256) void k_aggB(const float* __restrict__ T1,
    const int* __restrict__ cnt, const int* __restrict__ slot,
    const float4* __restrict__ nodal, float* __restrict__ u){
  int node = blockIdx.x*4 + (threadIdx.x >> 6);
  int lane = threadIdx.x & 63;
  if (node >= NN) return;
  int c = min(cnt[node], CAP);
  const int* sl = slot + (size_t)node*CAP;
  const float* nf = (const float*)nodal;
  float acc = 0.f;
  for (int base = 0; base < c; base += 64){
    int rem = min(64, c - base);
    bool act = lane < rem;
    int s = act ? sl[base+lane] : 0;
    float dc = act ? nf[(size_t)s*4] : 0.f;
    for (int j = 0; j < rem; ++j){
      int sb    = __shfl(s, j);
      float dcb = __shfl(dc, j);
      acc = fmaf(dcb, T1[(size_t)sb*64 + lane], acc);
    }
  }
  u[(size_t)node*64 + lane] = -2.f * nodal[node].x * acc;
}

// ---------------- tiled GEMV helpers ----------------
__device__ __forceinline__ void load_tile(const float* __restrict__ gsrc, int r0,
                                          float (*__restrict__ sm)[TP], int tid){
  #pragma unroll
  for (int i = 0; i < 4; ++i){
    int idx = i*256 + tid;
    int r = idx >> 4, c4 = idx & 15;
    float4 v = make_float4(0.f,0.f,0.f,0.f);
    if (r0 + r < NN) v = *(const float4*)&gsrc[(size_t)(r0+r)*64 + c4*4];
    *(float4*)&sm[r][c4*4] = v;
  }
}

__device__ __forceinline__ void load_w(const float* __restrict__ w,
                                       float (*__restrict__ sm)[TP], int tid){
  #pragma unroll
  for (int i = 0; i < 4; ++i){
    int idx = i*256 + tid;
    int r = idx >> 4, c4 = idx & 15;
    *(float4*)&sm[r][c4*4] = *(const float4*)&w[(size_t)r*64 + c4*4];
  }
}

__device__ __forceinline__ void gemv_tile(const float (*__restrict__ sA)[TP],
                                          const float (*__restrict__ sW)[TP],
                                          float4 o[4], int r4, int c4){
  #pragma unroll 4
  for (int k4 = 0; k4 < 16; ++k4){
    float4 w0 = *(const float4*)&sW[k4*4+0][c4*4];
    float4 w1 = *(const float4*)&sW[k4*4+1][c4*4];
    float4 w2 = *(const float4*)&sW[k4*4+2][c4*4];
    float4 w3 = *(const float4*)&sW[k4*4+3][c4*4];
    #pragma unroll
    for (int i = 0; i < 4; ++i){
      float4 a = *(const float4*)&sA[r4*4+i][k4*4];
      o[i].x = fmaf(a.x,w0.x, fmaf(a.y,w1.x, fmaf(a.z,w2.x, fmaf(a.w,w3.x, o[i].x))));
      o[i].y = fmaf(a.x,w0.y, fmaf(a.y,w1.y, fmaf(a.z,w2.y, fmaf(a.w,w3.y, o[i].y))));
      o[i].z = fmaf(a.x,w0.z, fmaf(a.y,w1.z, fmaf(a.z,w2.z, fmaf(a.w,w3.z, o[i].z))));
      o[i].w = fmaf(a.x,w0.w, fmaf(a.y,w1.w, fmaf(a.z,w2.w, fmaf(a.w,w3.w, o[i].w))));
    }
  }
}

__device__ __forceinline__ void zero4(float4 o[4]){
  #pragma unroll
  for (int i=0;i<4;++i) o[i] = make_float4(0.f,0.f,0.f,0.f);
}

__device__ __forceinline__ void acc_elu(float4 res[4], const float4 o[4], float4 b, float w){
  #pragma unroll
  for (int i=0;i<4;++i){
    res[i].x += w * eluf(o[i].x + b.x);
    res[i].y += w * eluf(o[i].y + b.y);
    res[i].z += w * eluf(o[i].z + b.z);
    res[i].w += w * eluf(o[i].w + b.w);
  }
}

// ---------------- epilogue: 9 GEMVs + elu-combine ----------------
__global__ __launch_bounds__(256) void k_epi(
    const float* __restrict__ x, const float* __restrict__ wts,
    const float* __restrict__ W_mlp, const float* __restrict__ b_mlp,
    const float* __restrict__ Wl, const float* __restrict__ Wr, const float* __restrict__ b_sage,
    const float* __restrict__ W_gcn, const float* __restrict__ b_gcn,
    const float* __restrict__ W_gat, const float* __restrict__ b_gat,
    const float* __restrict__ W_cheb, const float* __restrict__ b_cheb,
    const float* __restrict__ W_gin, const float* __restrict__ b_gin,
    const float4* __restrict__ nodal,
    const float* __restrict__ nsum, const float* __restrict__ T1,
    const float* __restrict__ v1, const float* __restrict__ g, const float* __restrict__ u,
    float* __restrict__ out){
  __shared__ float sX[64][TP];
  __shared__ float sA[64][TP];
  __shared__ float sW[64][TP];
  int tid = threadIdx.x, r0 = blockIdx.x*64;
  int c4 = tid & 15, r4 = tid >> 4;
  float w0 = wts[0], w1 = wts[1], w2 = wts[2], w3 = wts[3], w4 = wts[4], w5 = wts[5];
  const float* nf = (const float*)nodal;

  float4 res[4]; zero4(res);
  float4 o[4];

  // --- mlp ---
  load_tile(x, r0, sX, tid);
  load_w(W_mlp, sW, tid);
  __syncthreads();
  zero4(o);
  gemv_tile(sX, sW, o, r4, c4);
  acc_elu(res, o, *(const float4*)&b_mlp[c4*4], w0);
  __syncthreads();
  // --- sage: x@Wr + nmean@Wl ---
  load_w(Wr, sW, tid);
  __syncthreads();
  zero4(o);
  gemv_tile(sX, sW, o, r4, c4);
  __syncthreads();
  load_w(Wl, sW, tid);
  #pragma unroll
  for (int i=0;i<4;++i){   // stage nmean = nsum * dinvc^2
    int idx=i*256+tid; int r=idx>>4, cc=idx&15; int row=r0+r;
    float4 v = make_float4(0.f,0.f,0.f,0.f);
    if (row < NN){
      float dc = nf[(size_t)row*4];
      float sc = dc*dc;
      v = *(const float4*)&nsum[(size_t)row*64 + cc*4];
      v.x*=sc; v.y*=sc; v.z*=sc; v.w*=sc;
    }
    *(float4*)&sA[r][cc*4]=v;
  }
  __syncthreads();
  gemv_tile(sA, sW, o, r4, c4);
  acc_elu(res, o, *(const float4*)&b_sage[c4*4], w1);
  __syncthreads();
  // --- cheb: x@W0 + T1@W1 + T2@W2, T2 = u - x ---
  load_w(W_cheb, sW, tid);
  __syncthreads();
  zero4(o);
  gemv_tile(sX, sW, o, r4, c4);
  __syncthreads();
  load_w(W_cheb + 4096, sW, tid);
  load_tile(T1, r0, sA, tid);
  __syncthreads();
  gemv_tile(sA, sW, o, r4, c4);
  __syncthreads();
  load_w(W_cheb + 8192, sW, tid);
  #pragma unroll
  for (int i=0;i<4;++i){   // stage T2 = u - x
    int idx=i*256+tid; int r=idx>>4, cc=idx&15; int row=r0+r;
    float4 v = make_float4(0.f,0.f,0.f,0.f);
    if (row < NN) v = *(const float4*)&u[(size_t)row*64 + cc*4];
    float4 xv = *(const float4*)&sX[r][cc*4];
    v.x-=xv.x; v.y-=xv.y; v.z-=xv.z; v.w-=xv.w;
    *(float4*)&sA[r][cc*4]=v;
  }
  __syncthreads();
  gemv_tile(sA, sW, o, r4, c4);
  acc_elu(res, o, *(const float4*)&b_cheb[c4*4], w4);
  __syncthreads();
  // --- gcn: v1@W_gcn ---
  load_w(W_gcn, sW, tid);
  load_tile(v1, r0, sA, tid);
  __syncthreads();
  zero4(o);
  gemv_tile(sA, sW, o, r4, c4);
  acc_elu(res, o, *(const float4*)&b_gcn[c4*4], w2);
  __syncthreads();
  // --- gat: g@W_gat ---
  load_w(W_gat, sW, tid);
  load_tile(g, r0, sA, tid);
  __syncthreads();
  zero4(o);
  gemv_tile(sA, sW, o, r4, c4);
  acc_elu(res, o, *(const float4*)&b_gat[c4*4], w3);
  __syncthreads();
  // --- gin: (x+nsum)@W_gin ---
  load_w(W_gin, sW, tid);
  #pragma unroll
  for (int i=0;i<4;++i){
    int idx=i*256+tid; int r=idx>>4, cc=idx&15; int row=r0+r;
    float4 v = make_float4(0.f,0.f,0.f,0.f);
    if (row < NN) v = *(const float4*)&nsum[(size_t)row*64 + cc*4];
    float4 xv = *(const float4*)&sX[r][cc*4];
    v.x+=xv.x; v.y+=xv.y; v.z+=xv.z; v.w+=xv.w;
    *(float4*)&sA[r][cc*4]=v;
  }
  __syncthreads();
  zero4(o);
  gemv_tile(sA, sW, o, r4, c4);
  acc_elu(res, o, *(const float4*)&b_gin[c4*4], w5);
  // --- store ---
  #pragma unroll
  for (int i=0;i<4;++i){
    int row = r0 + r4*4 + i;
    if (row < NN) *(float4*)&out[(size_t)row*64 + c4*4] = res[i];
  }
}

extern "C" void kernel_launch(void* const* d_in, const int* in_sizes, int n_in,
                              void* d_out, int out_size, void* d_ws, size_t ws_size,
                              hipStream_t stream){
  const float* x      = (const float*)d_in[0];
  const float* wts    = (const float*)d_in[1];
  const float* W_mlp  = (const float*)d_in[2];
  const float* b_mlp  = (const float*)d_in[3];
  const float* Wl     = (const float*)d_in[4];
  const float* Wr     = (const float*)d_in[5];
  const float* b_sage = (const float*)d_in[6];
  const float* W_gcn  = (const float*)d_in[7];
  const float* b_gcn  = (const float*)d_in[8];
  const float* W_gat  = (const float*)d_in[9];
  const float* a_src  = (const float*)d_in[10];
  const float* a_dst  = (const float*)d_in[11];
  const float* b_gat  = (const float*)d_in[12];
  const float* W_cheb = (const float*)d_in[13];
  const float* b_cheb = (const float*)d_in[14];
  const float* W_gin  = (const float*)d_in[15];
  const float* b_gin  = (const float*)d_in[16];
  const int*   ei     = (const int*)d_in[17];
  const int* srcp = ei;
  const int* dstp = ei + NE;

  float* wsf  = (float*)d_ws;
  int*  cnt   = (int*)d_ws;
  int*  slot  = (int*)(wsf + O_SLOT);
  float4* nodal = (float4*)(wsf + O_NODAL);
  float* va   = wsf + O_VA;
  float* vb   = wsf + O_VB;
  float* nsum = wsf + O_NS;
  float* T1   = wsf + O_T1;
  float* v1   = wsf + O_V1;
  float* g    = wsf + O_G;
  float* u    = wsf + O_U;
  float* out  = (float*)d_out;

  hipMemsetAsync(cnt, 0, NN*sizeof(int), stream);
  k_scatter <<<3125, 256, 0, stream>>>(srcp, dstp, cnt, slot);
  k_va      <<<1,     64, 0, stream>>>(W_gat, a_src, a_dst, va, vb);
  k_nodal   <<<3125, 256, 0, stream>>>(x, cnt, va, vb, nodal);
  k_aggA    <<<12500,256, 0, stream>>>(x, cnt, slot, nodal, nsum, T1, v1, g);
  k_aggB    <<<12500,256, 0, stream>>>(T1, cnt, slot, nodal, u);
  k_epi     <<<782,  256, 0, stream>>>(x, wts, W_mlp, b_mlp, Wl, Wr, b_sage,
                                       W_gcn, b_gcn, W_gat, b_gat,
                                       W_cheb, b_cheb, W_gin, b_gin,
                                       nodal, nsum, T1, v1, g, u, out);
}

// Round 3
// 309.234 us; speedup vs baseline: 1.4279x; 1.2158x over previous
//
#include <hip/hip_runtime.h>
#include <cstdint>
#include <cstddef>

#define NN 50000
#define NE 800000
#define CAP 96      // max in-degree bucket (Poisson(16): P(deg>=96) ~ 1e-42)

// ---------------- ws layout (units of 4 bytes) ----------------
constexpr size_t O_CNT   = 0;                        // int[NN]
constexpr size_t O_SLOT  = 50048;                    // int[NN*CAP]
constexpr size_t O_NODAL = O_SLOT + (size_t)NN*CAP;  // float4[NN] {dinvc,dinv,el,er}
constexpr size_t O_VA    = O_NODAL + 200000;         // 64
constexpr size_t O_VB    = O_VA + 64;                // 64
constexpr size_t O_NS    = O_VB + 64;                // nsum [N,64]
constexpr size_t O_T1    = O_NS + 3200000;
constexpr size_t O_V1    = O_T1 + 3200000;           // gcn A-vector
constexpr size_t O_G     = O_V1 + 3200000;           // gat A-vector
constexpr size_t O_U     = O_G  + 3200000;           // -2*dinvc*aggT (T2 = u - x)
constexpr size_t O_T1B   = O_U  + 3200000;           // ushort[N*64] bf16 copy of T1
// total ~90.6 MB (ws >= 110 MB known-good from round 0)

typedef __attribute__((ext_vector_type(8))) short short8;   // 8 bf16 (4 VGPRs)
typedef __attribute__((ext_vector_type(4))) float f32x4;

__device__ __forceinline__ float leaky02(float v){ return v >= 0.f ? v : 0.2f*v; }
__device__ __forceinline__ float eluf(float v){ return v > 0.f ? v : (__expf(v) - 1.f); }

__device__ __forceinline__ void split2(float f, unsigned short& h, unsigned short& l){
  unsigned u = __float_as_uint(f);
  unsigned short hh = (unsigned short)(u >> 16);
  float fh = __uint_as_float(((unsigned)hh) << 16);
  float fl = f - fh;                       // exact
  h = hh;
  l = (unsigned short)(__float_as_uint(fl) >> 16);
}

// ---------------- bucket build ----------------
__global__ void k_scatter(const int* __restrict__ src, const int* __restrict__ dst,
                          int* __restrict__ cnt, int* __restrict__ slot){
  int e = blockIdx.x*256 + threadIdx.x;
  if (e >= NE) return;
  int s = src[e], d = dst[e];
  int pos = atomicAdd(&cnt[d], 1);
  if (pos < CAP) slot[(size_t)d*CAP + pos] = s;
}

// ---------------- va = W_gat @ a_src, vb = W_gat @ a_dst ----------------
__global__ void k_va(const float* __restrict__ Wg, const float* __restrict__ a_src,
                     const float* __restrict__ a_dst, float* __restrict__ va, float* __restrict__ vb){
  int k = threadIdx.x;   // 64 threads
  float sa = 0.f, sb = 0.f;
  for (int j = 0; j < 64; ++j){
    float w = Wg[k*64 + j];
    sa = fmaf(w, a_src[j], sa);
    sb = fmaf(w, a_dst[j], sb);
  }
  va[k] = sa; vb[k] = sb;
}

// ---------------- per-node scalars: {dinvc, dinv, el, er} ----------------
__global__ __launch_bounds__(256) void k_nodal(const float* __restrict__ x,
    const int* __restrict__ cnt, const float* __restrict__ va, const float* __restrict__ vb,
    float4* __restrict__ nodal){
  int tid = threadIdx.x;
  int li = tid & 15;
  int row = blockIdx.x*16 + (tid >> 4);
  if (row >= NN) return;
  float4 hv = *(const float4*)&x[(size_t)row*64 + li*4];
  float4 av = *(const float4*)&va[li*4];
  float4 bv = *(const float4*)&vb[li*4];
  float ps = hv.x*av.x + hv.y*av.y + hv.z*av.z + hv.w*av.w;
  float pd = hv.x*bv.x + hv.y*bv.y + hv.z*bv.z + hv.w*bv.w;
  #pragma unroll
  for (int o = 1; o < 16; o <<= 1){ ps += __shfl_xor(ps, o); pd += __shfl_xor(pd, o); }
  if (li == 0){
    float c = (float)cnt[row];
    float dinv  = rsqrtf(c + 1.f);
    float dinvc = rsqrtf(fmaxf(c, 1.f));
    nodal[row] = make_float4(dinvc, dinv, ps, pd);
  }
}

// ---------------- pass A: fused gather of x -> nsum, T1(+bf16), v1(gcn), g(gat) ------
__global__ __launch_bounds__(256) void k_aggA(const float* __restrict__ x,
    const int* __restrict__ cnt, const int* __restrict__ slot,
    const float4* __restrict__ nodal,
    float* __restrict__ nsum, float* __restrict__ T1, unsigned short* __restrict__ T1b,
    float* __restrict__ v1, float* __restrict__ g){
  int node = blockIdx.x*4 + (threadIdx.x >> 6);
  int lane = threadIdx.x & 63;
  if (node >= NN) return;
  int c = min(cnt[node], CAP);
  const int* sl = slot + (size_t)node*CAP;
  float4 nn = nodal[node];         // {dinvc, dinv, el, er}
  float ern = nn.w;
  float a0 = 0.f, a1 = 0.f, a2 = 0.f, a3 = 0.f, zl = 0.f;
  for (int base = 0; base < c; base += 64){
    int rem = min(64, c - base);
    bool act = lane < rem;
    int s = act ? sl[base+lane] : 0;
    float4 ns = act ? nodal[s] : make_float4(0.f,0.f,0.f,0.f);
    float p = act ? __expf(fminf(leaky02(ns.z + ern), 60.f)) : 0.f;
    zl += p;
    for (int j = 0; j < rem; ++j){
      int sb    = __shfl(s, j);
      float dcb = __shfl(ns.x, j);
      float dvb = __shfl(ns.y, j);
      float pb  = __shfl(p, j);
      float v = x[(size_t)sb*64 + lane];
      a0 += v;
      a1 = fmaf(dcb, v, a1);
      a2 = fmaf(dvb, v, a2);
      a3 = fmaf(pb,  v, a3);
    }
  }
  #pragma unroll
  for (int o = 32; o > 0; o >>= 1) zl += __shfl_xor(zl, o);
  float xs = x[(size_t)node*64 + lane];
  float p_self = __expf(fminf(leaky02(nn.z + nn.w), 60.f));
  float rz = 1.f / (zl + p_self + 1e-16f);
  size_t off = (size_t)node*64 + lane;
  float t1 = -nn.x * a1;
  nsum[off] = a0;
  T1[off]   = t1;
  T1b[off]  = (unsigned short)(__float_as_uint(t1) >> 16);
  v1[off]   = nn.y*a2 + nn.y*nn.y*xs;
  g[off]    = (a3 + p_self*xs) * rz;
}

// ---------------- pass B: gather T1(bf16) -> u = -2*dinvc*Σ dinvc[s] T1[s] ----------
__global__ __launch_bounds__(256) void k_aggB(const unsigned short* __restrict__ T1b,
    const int* __restrict__ cnt, const int* __restrict__ slot,
    const float4* __restrict__ nodal, float* __restrict__ u){
  int node = blockIdx.x*4 + (threadIdx.x >> 6);
  int lane = threadIdx.x & 63;
  if (node >= NN) return;
  int c = min(cnt[node], CAP);
  const int* sl = slot + (size_t)node*CAP;
  const float* nf = (const float*)nodal;
  float acc = 0.f;
  for (int base = 0; base < c; base += 64){
    int rem = min(64, c - base);
    bool act = lane < rem;
    int s = act ? sl[base+lane] : 0;
    float dc = act ? nf[(size_t)s*4] : 0.f;
    for (int j = 0; j < rem; ++j){
      int sb    = __shfl(s, j);
      float dcb = __shfl(dc, j);
      float tv = __uint_as_float(((unsigned)T1b[(size_t)sb*64 + lane]) << 16);
      acc = fmaf(dcb, tv, acc);
    }
  }
  u[(size_t)node*64 + lane] = -2.f * nodal[node].x * acc;
}

// ---------------- epilogue: split-bf16 MFMA, 10 gemv-groups ----------------
// LDS: A (64 rows x 72 bf16, hi+lo) + Wt (transposed, 64 x 72, hi+lo) = 36.9 KB
#define SA 72

__global__ __launch_bounds__(256) void k_epi(
    const float* __restrict__ x, const float* __restrict__ wts,
    const float* __restrict__ W_mlp, const float* __restrict__ b_mlp,
    const float* __restrict__ Wl, const float* __restrict__ Wr, const float* __restrict__ b_sage,
    const float* __restrict__ W_gcn, const float* __restrict__ b_gcn,
    const float* __restrict__ W_gat, const float* __restrict__ b_gat,
    const float* __restrict__ W_cheb, const float* __restrict__ b_cheb,
    const float* __restrict__ W_gin, const float* __restrict__ b_gin,
    const float4* __restrict__ nodal,
    const float* __restrict__ nsum, const float* __restrict__ T1,
    const float* __restrict__ v1, const float* __restrict__ g, const float* __restrict__ u,
    float* __restrict__ out){
  __shared__ unsigned short Ah[64][SA];
  __shared__ unsigned short Al[64][SA];
  __shared__ unsigned short Bh[64][SA];
  __shared__ unsigned short Bl[64][SA];

  const int tid = threadIdx.x;
  const int r0  = blockIdx.x*64;
  const int mrow = (tid >> 6) * 16;      // wave's 16-row group
  const int q    = (tid & 63) >> 4;      // quad within wave
  const int ml   = tid & 15;
  const int rowbase = r0 + mrow;
  const float w0 = wts[0], w1 = wts[1], w2 = wts[2], w3 = wts[3], w4 = wts[4], w5 = wts[5];
  const float* nod = (const float*)nodal;

  // ---- staging helpers (lambdas) ----
  auto stageA = [&](const float* __restrict__ src){
    #pragma unroll
    for (int i = 0; i < 4; ++i){
      int idx = i*256 + tid;
      int r = idx >> 4, c4 = idx & 15;
      int row = r0 + r;
      float4 v = make_float4(0.f,0.f,0.f,0.f);
      if (row < NN) v = *(const float4*)&src[(size_t)row*64 + c4*4];
      unsigned short h0,h1,h2,h3,l0,l1,l2,l3;
      split2(v.x,h0,l0); split2(v.y,h1,l1); split2(v.z,h2,l2); split2(v.w,h3,l3);
      ushort4 hv; hv.x=h0; hv.y=h1; hv.z=h2; hv.w=h3;
      ushort4 lv; lv.x=l0; lv.y=l1; lv.z=l2; lv.w=l3;
      *(ushort4*)&Ah[r][c4*4] = hv;
      *(ushort4*)&Al[r][c4*4] = lv;
    }
  };
  auto stageW = [&](const float* __restrict__ w, const float* __restrict__ wsub){
    int n  = tid & 63;
    int kg = tid >> 6;            // 4 groups of 16 k
    short8 vh0, vh1, vl0, vl1;
    #pragma unroll
    for (int j = 0; j < 8; ++j){
      float f = w[(size_t)(kg*16 + j)*64 + n];
      if (wsub) f -= wsub[(size_t)(kg*16 + j)*64 + n];
      unsigned short hh, ll; split2(f, hh, ll);
      vh0[j] = (short)hh; vl0[j] = (short)ll;
    }
    #pragma unroll
    for (int j = 0; j < 8; ++j){
      float f = w[(size_t)(kg*16 + 8 + j)*64 + n];
      if (wsub) f -= wsub[(size_t)(kg*16 + 8 + j)*64 + n];
      unsigned short hh, ll; split2(f, hh, ll);
      vh1[j] = (short)hh; vl1[j] = (short)ll;
    }
    *(short8*)&Bh[n][kg*16]     = vh0;
    *(short8*)&Bh[n][kg*16 + 8] = vh1;
    *(short8*)&Bl[n][kg*16]     = vl0;
    *(short8*)&Bl[n][kg*16 + 8] = vl1;
  };

  short8 ah0, ah1, al0, al1;     // A fragments (kept across groups w/ same A)
  auto loadA = [&](){
    int m = mrow + ml;
    ah0 = *(const short8*)&Ah[m][q*8];
    ah1 = *(const short8*)&Ah[m][32 + q*8];
    al0 = *(const short8*)&Al[m][q*8];
    al1 = *(const short8*)&Al[m][32 + q*8];
  };
  auto group = [&](f32x4 acc[4]){
    #pragma unroll
    for (int nt = 0; nt < 4; ++nt){
      int n = nt*16 + ml;
      short8 bh0 = *(const short8*)&Bh[n][q*8];
      short8 bl0 = *(const short8*)&Bl[n][q*8];
      acc[nt] = __builtin_amdgcn_mfma_f32_16x16x32_bf16(ah0, bh0, acc[nt], 0, 0, 0);
      acc[nt] = __builtin_amdgcn_mfma_f32_16x16x32_bf16(ah0, bl0, acc[nt], 0, 0, 0);
      acc[nt] = __builtin_amdgcn_mfma_f32_16x16x32_bf16(al0, bh0, acc[nt], 0, 0, 0);
      short8 bh1 = *(const short8*)&Bh[n][32 + q*8];
      short8 bl1 = *(const short8*)&Bl[n][32 + q*8];
      acc[nt] = __builtin_amdgcn_mfma_f32_16x16x32_bf16(ah1, bh1, acc[nt], 0, 0, 0);
      acc[nt] = __builtin_amdgcn_mfma_f32_16x16x32_bf16(ah1, bl1, acc[nt], 0, 0, 0);
      acc[nt] = __builtin_amdgcn_mfma_f32_16x16x32_bf16(al1, bh1, acc[nt], 0, 0, 0);
    }
  };

  f32x4 res[4];
  #pragma unroll
  for (int i=0;i<4;++i) res[i] = (f32x4){0.f,0.f,0.f,0.f};

  auto emit = [&](const f32x4 acc[4], const float* __restrict__ bias, float wk){
    #pragma unroll
    for (int nt = 0; nt < 4; ++nt){
      float b = bias[nt*16 + ml];
      #pragma unroll
      for (int r = 0; r < 4; ++r) res[nt][r] += wk * eluf(acc[nt][r] + b);
    }
  };

  f32x4 accWr[4], accCheb[4], accGin[4], t[4];
  #pragma unroll
  for (int i=0;i<4;++i){
    accWr[i]=(f32x4){0.f,0.f,0.f,0.f}; accCheb[i]=(f32x4){0.f,0.f,0.f,0.f};
    accGin[i]=(f32x4){0.f,0.f,0.f,0.f};
  }

  // ---- A = x : W_mlp(emit), Wr(keep), W0-W2(keep), W_gin(keep) ----
  stageA(x); stageW(W_mlp, nullptr);
  __syncthreads();
  loadA();
  #pragma unroll
  for (int i=0;i<4;++i) t[i]=(f32x4){0.f,0.f,0.f,0.f};
  group(t); emit(t, b_mlp, w0);
  __syncthreads(); stageW(Wr, nullptr);            __syncthreads(); group(accWr);
  __syncthreads(); stageW(W_cheb, W_cheb + 8192);  __syncthreads(); group(accCheb);
  __syncthreads(); stageW(W_gin, nullptr);         __syncthreads(); group(accGin);
  // ---- A = nsum : W_gin (still staged) -> gin ; Wl -> sage ----
  __syncthreads(); stageA(nsum);
  __syncthreads(); loadA();
  group(accGin); emit(accGin, b_gin, w5);
  __syncthreads(); stageW(Wl, nullptr);
  __syncthreads();
  #pragma unroll
  for (int i=0;i<4;++i) t[i]=(f32x4){0.f,0.f,0.f,0.f};
  group(t);
  { // sage: res += w1 * elu(invd[row]*(nsum@Wl) + x@Wr + b)
    #pragma unroll
    for (int nt = 0; nt < 4; ++nt){
      float b = b_sage[nt*16 + ml];
      #pragma unroll
      for (int r = 0; r < 4; ++r){
        int row = rowbase + q*4 + r;
        int rowc = row < NN ? row : NN-1;
        float dc = nod[(size_t)rowc*4];       // dinvc
        float invd = dc*dc;                    // 1/max(deg,1)
        res[nt][r] += w1 * eluf(invd*t[nt][r] + accWr[nt][r] + b);
      }
    }
  }
  // ---- A = T1 : W1 -> cheb ----
  __syncthreads(); stageA(T1); stageW(W_cheb + 4096, nullptr);
  __syncthreads(); loadA(); group(accCheb);
  // ---- A = u : W2 -> cheb, emit ----
  __syncthreads(); stageA(u); stageW(W_cheb + 8192, nullptr);
  __syncthreads(); loadA(); group(accCheb); emit(accCheb, b_cheb, w4);
  // ---- A = v1 : W_gcn, emit ----
  __syncthreads(); stageA(v1); stageW(W_gcn, nullptr);
  __syncthreads(); loadA();
  #pragma unroll
  for (int i=0;i<4;++i) t[i]=(f32x4){0.f,0.f,0.f,0.f};
  group(t); emit(t, b_gcn, w2);
  // ---- A = g : W_gat, emit ----
  __syncthreads(); stageA(g); stageW(W_gat, nullptr);
  __syncthreads(); loadA();
  #pragma unroll
  for (int i=0;i<4;++i) t[i]=(f32x4){0.f,0.f,0.f,0.f};
  group(t); emit(t, b_gat, w3);

  // ---- store (C/D layout: col=lane&15, row=q*4+r) ----
  #pragma unroll
  for (int nt = 0; nt < 4; ++nt){
    int col = nt*16 + ml;
    #pragma unroll
    for (int r = 0; r < 4; ++r){
      int row = rowbase + q*4 + r;
      if (row < NN) out[(size_t)row*64 + col] = res[nt][r];
    }
  }
}

extern "C" void kernel_launch(void* const* d_in, const int* in_sizes, int n_in,
                              void* d_out, int out_size, void* d_ws, size_t ws_size,
                              hipStream_t stream){
  const float* x      = (const float*)d_in[0];
  const float* wts    = (const float*)d_in[1];
  const float* W_mlp  = (const float*)d_in[2];
  const float* b_mlp  = (const float*)d_in[3];
  const float* Wl     = (const float*)d_in[4];
  const float* Wr     = (const float*)d_in[5];
  const float* b_sage = (const float*)d_in[6];
  const float* W_gcn  = (const float*)d_in[7];
  const float* b_gcn  = (const float*)d_in[8];
  const float* W_gat  = (const float*)d_in[9];
  const float* a_src  = (const float*)d_in[10];
  const float* a_dst  = (const float*)d_in[11];
  const float* b_gat  = (const float*)d_in[12];
  const float* W_cheb = (const float*)d_in[13];
  const float* b_cheb = (const float*)d_in[14];
  const float* W_gin  = (const float*)d_in[15];
  const float* b_gin  = (const float*)d_in[16];
  const int*   ei     = (const int*)d_in[17];
  const int* srcp = ei;
  const int* dstp = ei + NE;

  float* wsf  = (float*)d_ws;
  int*  cnt   = (int*)d_ws;
  int*  slot  = (int*)(wsf + O_SLOT);
  float4* nodal = (float4*)(wsf + O_NODAL);
  float* va   = wsf + O_VA;
  float* vb   = wsf + O_VB;
  float* nsum = wsf + O_NS;
  float* T1   = wsf + O_T1;
  float* v1   = wsf + O_V1;
  float* g    = wsf + O_G;
  float* u    = wsf + O_U;
  unsigned short* T1b = (unsigned short*)(wsf + O_T1B);
  float* out  = (float*)d_out;

  hipMemsetAsync(cnt, 0, NN*sizeof(int), stream);
  k_scatter <<<3125, 256, 0, stream>>>(srcp, dstp, cnt, slot);
  k_va      <<<1,     64, 0, stream>>>(W_gat, a_src, a_dst, va, vb);
  k_nodal   <<<3125, 256, 0, stream>>>(x, cnt, va, vb, nodal);
  k_aggA    <<<12500,256, 0, stream>>>(x, cnt, slot, nodal, nsum, T1, T1b, v1, g);
  k_aggB    <<<12500,256, 0, stream>>>(T1b, cnt, slot, nodal, u);
  k_epi     <<<782,  256, 0, stream>>>(x, wts, W_mlp, b_mlp, Wl, Wr, b_sage,
                                       W_gcn, b_gcn, W_gat, b_gat,
                                       W_cheb, b_cheb, W_gin, b_gin,
                                       nodal, nsum, T1, v1, g, u, out);
}